// Round 13
// baseline (678.848 us; speedup 1.0000x reference)
//
#include <hip/hip_runtime.h>
#include <math.h>

typedef unsigned short u16;
typedef _Float16 f16;
typedef __attribute__((ext_vector_type(8))) _Float16 f16x8;
typedef __attribute__((ext_vector_type(4))) float f32x4;
typedef float4 __attribute__((aligned(4))) float4u;   // 4B-aligned vector load

constexpr int P0 = 6891, P1 = 1724, P2 = 432, P3 = 109, P4 = 28;
constexpr int P0p = 6912;

// ---- constexpr workspace layout (bytes, all 256-aligned) ----
constexpr size_t OFF_ZB   = 0;
constexpr size_t OFF_MD0  = OFF_ZB   + 256;
constexpr size_t OFF_MU0  = OFF_MD0  + (size_t)1792 * 6912 * 2;
constexpr size_t OFF_MD1  = OFF_MU0  + (size_t)6912 * 1792 * 2;
constexpr size_t OFF_MU1  = OFF_MD1  + (size_t)512 * 1792 * 2;
constexpr size_t OFF_MD2  = OFF_MU1  + (size_t)1792 * 512 * 2;
constexpr size_t OFF_MU2  = OFF_MD2  + (size_t)128 * 512 * 2;
constexpr size_t OFF_MD3  = OFF_MU2  + (size_t)512 * 128 * 2;
constexpr size_t OFF_MU3  = OFF_MD3  + (size_t)128 * 128 * 2;
constexpr size_t OFF_WE1  = OFF_MU3  + (size_t)128 * 128 * 2;
constexpr size_t OFF_WE2  = OFF_WE1  + (size_t)32 * 192 * 2;
constexpr size_t OFF_WE3  = OFF_WE2  + (size_t)64 * 320 * 2;
constexpr size_t OFF_WD0  = OFF_WE3  + (size_t)128 * 576 * 2;
constexpr size_t OFF_WD1  = OFF_WD0  + (size_t)64 * 1152 * 2;
constexpr size_t OFF_WD2  = OFF_WD1  + (size_t)32 * 576 * 2;
constexpr size_t OFF_WD3  = OFF_WD2  + (size_t)32 * 320 * 2;
constexpr size_t OFF_WT0  = OFF_WD3  + (size_t)16 * 320 * 2;
constexpr size_t OFF_XT   = OFF_WT0  + (size_t)16 * 128 * 2;
constexpr size_t OFF_FCP  = OFF_XT   + (size_t)6912 * 64 * 8 * 2;   // fp16 x-table [P0p][64][8]
constexpr size_t OFF_B0   = OFF_FCP  + (size_t)28 * 8192 * 4;
constexpr size_t OFF_B1   = OFF_B0   + (size_t)1024 * 6912 * 2;
constexpr size_t OFF_PB   = OFF_B1   + (size_t)6912 * 2048 * 2;
constexpr size_t OFF_END  = OFF_PB   + (size_t)14680064;            // legacy split-K partials

// ---- kprep segment sizes (items) ----
constexpr int CN_MD0 = 1792 * 864, CN_MU0 = 6912 * 224, CN_MD1 = 512 * 224,
              CN_MU1 = 1792 * 64, CN_MD2 = 128 * 64, CN_MU2 = 512 * 16,
              CN_MD3 = 128 * 16, CN_MU3 = 128 * 16,
              CN_W1 = 32 * 24, CN_W2 = 64 * 40, CN_W3 = 128 * 72,
              CN_V0 = 64 * 144, CN_V1 = 32 * 72, CN_V2 = 32 * 40, CN_V3 = 16 * 40,
              CN_W0 = 16 * 16, CN_XT = 6912 * 64, CN_ZB = 32;
constexpr int CN_TOTAL = CN_MD0 + CN_MU0 + CN_MD1 + CN_MU1 + CN_MD2 + CN_MU2 +
                         CN_MD3 + CN_MU3 + CN_W1 + CN_W2 + CN_W3 + CN_V0 + CN_V1 +
                         CN_V2 + CN_V3 + CN_W0 + CN_XT + CN_ZB;

__device__ __forceinline__ u16 f2h(float v) {
  f16 h = (f16)v;
  return __builtin_bit_cast(u16, h);
}
__device__ __forceinline__ float h2f(u16 u) {
  return (float)__builtin_bit_cast(f16, u);
}
__device__ __forceinline__ float eluf(float v) { return v > 0.f ? v : expm1f(v); }

__device__ __forceinline__ void gload16(const void* g, void* lds) {
  __builtin_amdgcn_global_load_lds(
      (const __attribute__((address_space(1))) unsigned int*)g,
      (__attribute__((address_space(3))) unsigned int*)lds, 16, 0, 0);
}

// ---------------------------------------------------------------------------
// Fused preprocessing.
// ---------------------------------------------------------------------------
struct PrepSrc {
  const float *D0, *U0, *D1, *U1, *D2, *U2, *D3, *U3;
  const float *We1, *We2, *We3, *Wd0, *Wd1, *Wd2, *Wd3;
  const float *We0, *x;
};

// M [P][Q] fp32 -> [Ppad][Qpad] fp16 zero-pad, 16B-chunk XOR-swizzled by p&7.
__device__ __forceinline__ void conv_m_item(const float* __restrict__ M, u16* __restrict__ out,
                                            int idx, int P, int Q, int Qpad) {
  int cpr = Qpad >> 3;
  int p = idx / cpr, cq = idx - p * cpr;
  int w0 = (cq << 3) & ~63;
  int q0 = w0 + (((cq & 7) ^ (p & 7)) << 3);
  uint4 pk;
  if (p < P && q0 + 8 <= Q) {
    const float* s = M + (size_t)p * Q + q0;
    float4 va = *(const float4u*)s;
    float4 vb = *(const float4u*)(s + 4);
    pk.x = f2h(va.x) | ((unsigned)f2h(va.y) << 16);
    pk.y = f2h(va.z) | ((unsigned)f2h(va.w) << 16);
    pk.z = f2h(vb.x) | ((unsigned)f2h(vb.y) << 16);
    pk.w = f2h(vb.z) | ((unsigned)f2h(vb.w) << 16);
  } else {
    u16 v[8];
#pragma unroll
    for (int j = 0; j < 8; ++j) {
      int q = q0 + j;
      float f = (p < P && q < Q) ? M[(size_t)p * Q + q] : 0.f;
      v[j] = f2h(f);
    }
    pk.x = v[0] | ((unsigned)v[1] << 16); pk.y = v[2] | ((unsigned)v[3] << 16);
    pk.z = v[4] | ((unsigned)v[5] << 16); pk.w = v[6] | ((unsigned)v[7] << 16);
  }
  *(uint4*)(out + ((size_t)idx << 3)) = pk;
}

// W [K][F] fp32 -> Wt [F][Kpad] fp16 transposed, zero-pad, swizzled by co&7.
__device__ __forceinline__ void conv_w_item(const float* __restrict__ W, u16* __restrict__ out,
                                            int idx, int K, int F, int Kpad) {
  int cpr = Kpad >> 3;
  int co = idx / cpr, ck = idx - co * cpr;
  int w0 = (ck << 3) & ~63;
  int k0 = w0 + (((ck & 7) ^ (co & 7)) << 3);
  u16 v[8];
#pragma unroll
  for (int j = 0; j < 8; ++j) {
    int k = k0 + j;
    float f = (k < K) ? W[(size_t)k * F + co] : 0.f;
    v[j] = f2h(f);
  }
  uint4 pk;
  pk.x = v[0] | ((unsigned)v[1] << 16); pk.y = v[2] | ((unsigned)v[3] << 16);
  pk.z = v[4] | ((unsigned)v[5] << 16); pk.w = v[6] | ((unsigned)v[7] << 16);
  *(uint4*)(out + ((size_t)idx << 3)) = pk;
}

// We0 [27 = s*3+c][16] -> Wt0 [16 co][128 k], k = s*8+c (FIN padded 3->8), swizzled.
__device__ __forceinline__ void conv_w0_item(const float* __restrict__ W, u16* __restrict__ out,
                                             int idx) {
  int co = idx >> 4, ck = idx & 15;
  int w0 = (ck << 3) & ~63;
  int k0 = w0 + (((ck & 7) ^ (co & 7)) << 3);
  u16 v[8];
#pragma unroll
  for (int j = 0; j < 8; ++j) {
    int k = k0 + j;
    int s = k >> 3, c = k & 7;
    float f = (s < 9 && c < 3) ? W[(size_t)(s * 3 + c) * 16 + co] : 0.f;
    v[j] = f2h(f);
  }
  uint4 pk;
  pk.x = v[0] | ((unsigned)v[1] << 16); pk.y = v[2] | ((unsigned)v[3] << 16);
  pk.z = v[4] | ((unsigned)v[5] << 16); pk.w = v[6] | ((unsigned)v[7] << 16);
  *(uint4*)(out + ((size_t)idx << 3)) = pk;
}

__global__ __launch_bounds__(256) void kprep(PrepSrc a, char* __restrict__ ws) {
  int i = blockIdx.x * 256 + threadIdx.x;
  if (i >= CN_TOTAL) return;
  if (i < CN_MD0) { conv_m_item(a.D0, (u16*)(ws + OFF_MD0), i, P1, P0, 6912); return; }
  i -= CN_MD0;
  if (i < CN_MU0) { conv_m_item(a.U0, (u16*)(ws + OFF_MU0), i, P0, P1, 1792); return; }
  i -= CN_MU0;
  if (i < CN_XT) {  // x [64][P0][3] fp32 -> xt16 [P0p][64][8] fp16 (f 3..7 = 0)
    u16* xt = (u16*)(ws + OFF_XT);
    int p = i >> 6, b = i & 63;
    float v0 = 0, v1 = 0, v2 = 0;
    if (p < P0) { const float* s = a.x + ((size_t)b * P0 + p) * 3; v0 = s[0]; v1 = s[1]; v2 = s[2]; }
    uint4 pk;
    pk.x = f2h(v0) | ((unsigned)f2h(v1) << 16);
    pk.y = f2h(v2);
    pk.z = 0; pk.w = 0;
    *(uint4*)(xt + ((size_t)i << 3)) = pk;
    return;
  }
  i -= CN_XT;
  if (i < CN_MD1) { conv_m_item(a.D1, (u16*)(ws + OFF_MD1), i, P2, P1, 1792); return; }
  i -= CN_MD1;
  if (i < CN_MU1) { conv_m_item(a.U1, (u16*)(ws + OFF_MU1), i, P1, P2, 512); return; }
  i -= CN_MU1;
  if (i < CN_MD2) { conv_m_item(a.D2, (u16*)(ws + OFF_MD2), i, P3, P2, 512); return; }
  i -= CN_MD2;
  if (i < CN_MU2) { conv_m_item(a.U2, (u16*)(ws + OFF_MU2), i, P2, P3, 128); return; }
  i -= CN_MU2;
  if (i < CN_MD3) { conv_m_item(a.D3, (u16*)(ws + OFF_MD3), i, P4, P3, 128); return; }
  i -= CN_MD3;
  if (i < CN_MU3) { conv_m_item(a.U3, (u16*)(ws + OFF_MU3), i, P3, P4, 128); return; }
  i -= CN_MU3;
  if (i < CN_W1) { conv_w_item(a.We1, (u16*)(ws + OFF_WE1), i, 144, 32, 192); return; }
  i -= CN_W1;
  if (i < CN_W2) { conv_w_item(a.We2, (u16*)(ws + OFF_WE2), i, 288, 64, 320); return; }
  i -= CN_W2;
  if (i < CN_W3) { conv_w_item(a.We3, (u16*)(ws + OFF_WE3), i, 576, 128, 576); return; }
  i -= CN_W3;
  if (i < CN_V0) { conv_w_item(a.Wd0, (u16*)(ws + OFF_WD0), i, 1152, 64, 1152); return; }
  i -= CN_V0;
  if (i < CN_V1) { conv_w_item(a.Wd1, (u16*)(ws + OFF_WD1), i, 576, 32, 576); return; }
  i -= CN_V1;
  if (i < CN_V2) { conv_w_item(a.Wd2, (u16*)(ws + OFF_WD2), i, 288, 32, 320); return; }
  i -= CN_V2;
  if (i < CN_V3) { conv_w_item(a.Wd3, (u16*)(ws + OFF_WD3), i, 288, 16, 320); return; }
  i -= CN_V3;
  if (i < CN_W0) { conv_w0_item(a.We0, (u16*)(ws + OFF_WT0), i); return; }
  i -= CN_W0;
  ((unsigned long long*)(ws + OFF_ZB))[i] = 0ull;  // zb
}

// ---------------------------------------------------------------------------
// kgemm8: 256x256 tile, BK=32, 512 thr (8 waves 2x4), 2-buffer counted-vmcnt
// pipeline at 2 blocks/CU (64 KB LDS): per K-step
//   vmcnt(4|0) ; barrier ; bv + 4 phases{2 ds_read, 8-MFMA setprio cluster} ;
//   barrier ; stage(k+2 -> buf k&1).
// Cross-block TLP hides the stage latency (m97 regime). A and B FM-swizzled
// [rows][Kpad]. C plain [M][N] fp16. grid (M/256, N/256).
// ---------------------------------------------------------------------------
__global__ __launch_bounds__(512, 4) void kgemm8(const u16* __restrict__ A, const u16* __restrict__ B,
                                                 u16* __restrict__ C, int Kpad, int N) {
  __shared__ u16 lds[2 * 16384];   // 2 bufs x (A 8192 + B 8192) u16 = 64 KB
  const int t = threadIdx.x, l = t & 63;
  const int w = t >> 6, wr = w >> 2, wc = w & 3;
  const int pt = blockIdx.x * 256, nt = blockIdx.y * 256;
  const int NK = Kpad >> 5;

  f32x4 acc[8][4];
#pragma unroll
  for (int a = 0; a < 8; ++a)
#pragma unroll
    for (int b = 0; b < 4; ++b) acc[a][b] = (f32x4){0.f, 0.f, 0.f, 0.f};

  // ph 0/1: A halves; ph 2/3: B halves. Src read undoes producer swizzle.
  auto stage_chunk = [&](int qq, int ks, int ph) {
    int s = t + (ph & 1) * 512;
    int row = (s & 15) | ((s >> 6) << 4);
    int kc = (s >> 4) & 3;
    int slot = ((((ks & 1) << 2) + kc) ^ (row & 7));
    const u16* src;
    int base;
    if (ph < 2) {
      src = A + (size_t)(pt + row) * Kpad + ((ks >> 1) << 6) + (slot << 3);
      base = qq * 16384 + (s & ~63) * 8;
    } else {
      src = B + (size_t)(nt + row) * Kpad + ((ks >> 1) << 6) + (slot << 3);
      base = qq * 16384 + 8192 + (s & ~63) * 8;
    }
    gload16(src, &lds[base]);
  };

#pragma unroll
  for (int ph = 0; ph < 4; ++ph) stage_chunk(0, 0, ph);
  if (NK > 1)
#pragma unroll
    for (int ph = 0; ph < 4; ++ph) stage_chunk(1, 1, ph);

  for (int k = 0; k < NK; ++k) {
    // Stage k must have landed. In flight beyond it: stage k+1 (4 loads) if
    // issued; at the last iteration nothing newer exists -> full drain.
    if (k == NK - 1) asm volatile("s_waitcnt vmcnt(0)" ::: "memory");
    else             asm volatile("s_waitcnt vmcnt(4)" ::: "memory");
    __builtin_amdgcn_s_barrier();
    __builtin_amdgcn_sched_barrier(0);
    const u16* bufA = &lds[(k & 1) * 16384];
    const u16* bufB = bufA + 8192;

    f16x8 bv[4];
#pragma unroll
    for (int nf = 0; nf < 4; ++nf)
      bv[nf] = *(const f16x8*)&bufB[(wc * 4 + nf) * 512 + l * 8];

#pragma unroll
    for (int ph = 0; ph < 4; ++ph) {
      f16x8 a0 = *(const f16x8*)&bufA[(wr * 8 + 2 * ph) * 512 + l * 8];
      f16x8 a1 = *(const f16x8*)&bufA[(wr * 8 + 2 * ph + 1) * 512 + l * 8];
      __builtin_amdgcn_s_setprio(1);
#pragma unroll
      for (int nf = 0; nf < 4; ++nf) {
        acc[2 * ph][nf]     = __builtin_amdgcn_mfma_f32_16x16x32_f16(a0, bv[nf], acc[2 * ph][nf], 0, 0, 0);
        acc[2 * ph + 1][nf] = __builtin_amdgcn_mfma_f32_16x16x32_f16(a1, bv[nf], acc[2 * ph + 1][nf], 0, 0, 0);
      }
      __builtin_amdgcn_s_setprio(0);
      __builtin_amdgcn_sched_barrier(0);
    }

    if (k + 2 < NK) {   // uniform condition
      __builtin_amdgcn_s_barrier();          // all waves done reading buf[k&1]
      __builtin_amdgcn_sched_barrier(0);
#pragma unroll
      for (int ph = 0; ph < 4; ++ph) stage_chunk(k & 1, k + 2, ph);
    }
  }

#pragma unroll
  for (int mf = 0; mf < 8; ++mf) {
    int prow = pt + wr * 128 + mf * 16 + ((l >> 4) << 2);
#pragma unroll
    for (int nf = 0; nf < 4; ++nf) {
      int ncol = nt + wc * 64 + nf * 16 + (l & 15);
#pragma unroll
      for (int rg = 0; rg < 4; ++rg)
        C[(size_t)(prow + rg) * N + ncol] = f2h(acc[mf][nf][rg]);
    }
  }
}

// ---------------------------------------------------------------------------
// Unified MFMA GEMM — single-buffered 2-barrier loop (unchanged from r8).
// ---------------------------------------------------------------------------
template <bool GATHER, int TN, int LOG_FIN, bool DO_ELU, int OUT_MODE = 0>
__global__ __launch_bounds__(256) void kgemm(const u16* __restrict__ Asrc, const u16* __restrict__ Bsrc,
                                             const int* __restrict__ S, const float* __restrict__ bias,
                                             u16* __restrict__ Cout, const u16* __restrict__ zb,
                                             int Kpad, int Pn, int PpadC, int N) {
  constexpr int NF = TN / 16;
  __shared__ u16 Ash[128 * 64];
  __shared__ u16 Bsh[TN * 64];
  __shared__ int Sl[16 * 12];

  const int t = threadIdx.x, w = t >> 6, l = t & 63;
  int p0, b0 = 0, n0 = 0;
  if (GATHER) { p0 = blockIdx.x * 16; b0 = blockIdx.y * 8; n0 = blockIdx.z * TN; }
  else        { p0 = blockIdx.x * 128; n0 = blockIdx.y * 128; }

  if constexpr (GATHER) {
    for (int i = t; i < 144; i += 256) {
      int pp = p0 + i / 9;
      Sl[(i / 9) * 12 + (i % 9)] = (pp < Pn) ? S[pp * 9 + (i % 9)] : 0;
    }
    __syncthreads();
  }

  const int NK = Kpad >> 6;
  int NKs, ks0;
  if constexpr (GATHER) { NKs = NK; ks0 = 0; }
  else                  { NKs = NK / gridDim.z; ks0 = blockIdx.z * NKs; }
  f32x4 acc[2][NF];
#pragma unroll
  for (int a = 0; a < 2; ++a)
#pragma unroll
    for (int b = 0; b < NF; ++b) acc[a][b] = (f32x4){0.f, 0.f, 0.f, 0.f};

  auto stage = [&](int ks) {
#pragma unroll
    for (int g0 = 0; g0 < 4; ++g0) {
      int g = g0 * 4 + w;
      int r = g * 8 + (l >> 3);
      const u16* src;
      if constexpr (GATHER) {
        int c = (l & 7) ^ (r & 7);
        int k = ks * 64 + c * 8;
        int s = k >> LOG_FIN;
        if (s < 9) {
          int kk = k & ((1 << LOG_FIN) - 1);
          int sv = Sl[(r & 15) * 12 + s];
          src = Asrc + (((size_t)(sv << 6) + b0 + (r >> 4)) << LOG_FIN) + kk;
        } else src = zb;
      } else {
        src = Asrc + (size_t)(p0 + r) * Kpad + ks * 64 + (l & 7) * 8;
      }
      gload16(src, &Ash[g * 512]);
    }
#pragma unroll
    for (int g0 = 0; g0 < (TN / 8 + 3) / 4; ++g0) {
      int g = g0 * 4 + w;
      if (g < TN / 8) {
        int r = g * 8 + (l >> 3);
        const u16* src = Bsrc + (size_t)(n0 + r) * Kpad + ks * 64 + (l & 7) * 8;
        gload16(src, &Bsh[g * 512]);
      }
    }
  };

  auto compute = [&]() {
#pragma unroll
    for (int kh = 0; kh < 2; ++kh) {
      f16x8 av[2], bv[NF];
#pragma unroll
      for (int mf = 0; mf < 2; ++mf) {
        int r = w * 32 + mf * 16 + (l & 15);
        int c = kh * 4 + (l >> 4);
        av[mf] = *(const f16x8*)&Ash[r * 64 + ((c ^ (r & 7)) << 3)];
      }
#pragma unroll
      for (int nf = 0; nf < NF; ++nf) {
        int r = nf * 16 + (l & 15);
        int c = kh * 4 + (l >> 4);
        bv[nf] = *(const f16x8*)&Bsh[r * 64 + ((c ^ (r & 7)) << 3)];
      }
#pragma unroll
      for (int mf = 0; mf < 2; ++mf)
#pragma unroll
        for (int nf = 0; nf < NF; ++nf)
          acc[mf][nf] = __builtin_amdgcn_mfma_f32_16x16x32_f16(av[mf], bv[nf], acc[mf][nf], 0, 0, 0);
    }
  };

  for (int i = 0; i < NKs; ++i) {
    stage(ks0 + i);
    __syncthreads();
    compute();
    __syncthreads();
  }

  if constexpr (GATHER && OUT_MODE == 1) {
    u16* T = &Ash[0];   // viewed as [16][136]
    int co = l & 15;
    float bb = bias[co];
    int prow = (l >> 4) << 2;
#pragma unroll
    for (int mf = 0; mf < 2; ++mf) {
      int ncol = (w * 2 + mf) * 16 + co;
#pragma unroll
      for (int rg = 0; rg < 4; ++rg) {
        float v = acc[mf][0][rg] + bb;
        if (DO_ELU) v = eluf(v);
        if (p0 + prow + rg >= Pn - 1) v = 0.f;
        T[(prow + rg) * 136 + ncol] = f2h(v);
      }
    }
    __syncthreads();
    int r = t >> 4, c8 = (t & 15) << 3;
    uint4 pk = *(const uint4*)&T[r * 136 + c8];
    *(uint4*)(Cout + (size_t)(p0 + r) * (64 * TN) + (size_t)blockIdx.y * 128 + c8) = pk;
  } else if constexpr (GATHER) {
#pragma unroll
    for (int nf = 0; nf < NF; ++nf) {
      int co = n0 + nf * 16 + (l & 15);
      float bb = bias[co];
#pragma unroll
      for (int mf = 0; mf < 2; ++mf) {
        int b = b0 + w * 2 + mf;
        int n = b * N + co;
        int pbase = p0 + ((l >> 4) << 2);
        u16 hv[4];
#pragma unroll
        for (int rg = 0; rg < 4; ++rg) {
          float v = acc[mf][nf][rg] + bb;
          if (DO_ELU) v = eluf(v);
          if (pbase + rg >= Pn - 1) v = 0.f;
          hv[rg] = f2h(v);
        }
        int slot = ((pbase >> 3) & 7) ^ (n & 7);
        u16* dst = Cout + (size_t)n * PpadC + (pbase & ~63) + (slot << 3) + (pbase & 7);
        uint2 pk;
        pk.x = hv[0] | ((unsigned)hv[1] << 16);
        pk.y = hv[2] | ((unsigned)hv[3] << 16);
        *(uint2*)dst = pk;
      }
    }
  } else {
    u16* Cb = Cout + (size_t)blockIdx.z * ((size_t)gridDim.x * 128 * N);
#pragma unroll
    for (int mf = 0; mf < 2; ++mf) {
      int pb = p0 + w * 32 + mf * 16 + ((l >> 4) << 2);
#pragma unroll
      for (int nf = 0; nf < NF; ++nf) {
        int n = n0 + nf * 16 + (l & 15);
#pragma unroll
        for (int rg = 0; rg < 4; ++rg)
          Cb[(size_t)(pb + rg) * N + n] = f2h(acc[mf][nf][rg]);
      }
    }
  }
}

// Reduce split-K fp16 partial slices: out[i] = sum_z part[z*slice + i].
__global__ __launch_bounds__(256) void kred(const u16* __restrict__ part, u16* __restrict__ out,
                                            int mn8, int sk, size_t slice) {
  int i = blockIdx.x * 256 + threadIdx.x;
  if (i >= mn8) return;
  size_t base = (size_t)i * 8;
  float s[8] = {};
  for (int z = 0; z < sk; ++z) {
    uint4 u = *(const uint4*)(part + z * slice + base);
    s[0] += h2f((u16)u.x); s[1] += h2f((u16)(u.x >> 16));
    s[2] += h2f((u16)u.y); s[3] += h2f((u16)(u.y >> 16));
    s[4] += h2f((u16)u.z); s[5] += h2f((u16)(u.z >> 16));
    s[6] += h2f((u16)u.w); s[7] += h2f((u16)(u.w >> 16));
  }
  uint4 o;
  o.x = f2h(s[0]) | ((unsigned)f2h(s[1]) << 16);
  o.y = f2h(s[2]) | ((unsigned)f2h(s[3]) << 16);
  o.z = f2h(s[4]) | ((unsigned)f2h(s[5]) << 16);
  o.w = f2h(s[6]) | ((unsigned)f2h(s[7]) << 16);
  *(uint4*)(out + base) = o;
}

// ---------------------------------------------------------------------------
// FC encode split-K stage 1. grid (28, 2), 256 thr.
// ---------------------------------------------------------------------------
__global__ __launch_bounds__(256) void kfc_enc1(const u16* __restrict__ h, const float* __restrict__ W,
                                                float* __restrict__ partial) {
  __shared__ float hs[64][128];
  __shared__ float wsh[128][64];
  int p = blockIdx.x, nh = blockIdx.y, t = threadIdx.x;
  for (int i = t; i < 8192; i += 256) hs[i >> 7][i & 127] = h2f(h[(size_t)p * 8192 + i]);
  for (int i = t; i < 128 * 64; i += 256) {
    int kk = i >> 6, jj = i & 63;
    wsh[kk][jj] = W[(size_t)(p * 128 + kk) * 128 + nh * 64 + jj];
  }
  __syncthreads();
  int j = t & 63, bg = t >> 6;
  float acc[16] = {};
  for (int k = 0; k < 128; ++k) {
    float wv = wsh[k][j];
#pragma unroll
    for (int i = 0; i < 16; ++i) acc[i] = fmaf(hs[bg * 16 + i][k], wv, acc[i]);
  }
#pragma unroll
  for (int i = 0; i < 16; ++i)
    partial[((size_t)p * 64 + bg * 16 + i) * 128 + nh * 64 + j] = acc[i];
}

// FC decode (fused z-reduction). grid (14, 8).
__global__ __launch_bounds__(256) void kfc_dec(const float* __restrict__ partial,
                                               const float* __restrict__ bfe, float* __restrict__ z,
                                               const float* __restrict__ W,
                                               const float* __restrict__ bias, u16* __restrict__ out) {
  __shared__ float zs[8][128];
  int t = threadIdx.x, b0 = blockIdx.y * 8;
  for (int i = t; i < 8 * 128; i += 256) {
    int bb = i >> 7, j = i & 127;
    float s = bfe[j];
    for (int p = 0; p < 28; ++p) s += partial[(size_t)p * 8192 + (b0 + bb) * 128 + j];
    zs[bb][j] = s;
    if (blockIdx.x == 0) z[(b0 + bb) * 128 + j] = s;
  }
  __syncthreads();
  int m = blockIdx.x * 256 + t;
  float bb = bias[m];
  float acc[8];
#pragma unroll
  for (int i = 0; i < 8; ++i) acc[i] = bb;
  for (int k = 0; k < 128; ++k) {
    float wv = W[(size_t)k * 3584 + m];
#pragma unroll
    for (int i = 0; i < 8; ++i) acc[i] = fmaf(zs[i][k], wv, acc[i]);
  }
  int p = m >> 7, f = m & 127;
  int slot0 = p >> 3;
#pragma unroll
  for (int i = 0; i < 8; ++i) {
    int n = (b0 + i) * 128 + f;
    int slot = slot0 ^ (n & 7);
    out[(size_t)n * 128 + (slot << 3) + (p & 7)] = f2h(acc[i]);
  }
}

// ---------------------------------------------------------------------------
// final conv 16->3 identity; VM fp16 in [6912][1024], fp32 out [64][P0][3].
// ---------------------------------------------------------------------------
__global__ __launch_bounds__(256) void kfinal(const u16* __restrict__ x, const int* __restrict__ S,
                                              const float* __restrict__ W, const float* __restrict__ bias,
                                              float* __restrict__ out) {
  __shared__ float Wl[432];
  __shared__ int Sl[64 * 9];
  int t = threadIdx.x;
  for (int i = t; i < 432; i += 256) Wl[i] = W[i];
  int pblk = blockIdx.x * 64;
  for (int i = t; i < 64 * 9; i += 256) {
    int pp = pblk + i / 9;
    Sl[i] = (pp < P0) ? S[pp * 9 + (i % 9)] : 0;
  }
  __syncthreads();
  int lane = t & 63, w = t >> 6;
  int p = pblk + lane;
  float b0v = bias[0], b1v = bias[1], b2v = bias[2];
  int idxs[9];
#pragma unroll
  for (int s = 0; s < 9; ++s) idxs[s] = Sl[lane * 9 + s];
#pragma unroll
  for (int bi = 0; bi < 2; ++bi) {
    int b = blockIdx.y * 8 + w * 2 + bi;
    float a0 = b0v, a1 = b1v, a2 = b2v;
    for (int s = 0; s < 9; ++s) {
      const f16x8* xr = (const f16x8*)(x + ((size_t)idxs[s] * 64 + b) * 16);
      f16x8 v0 = xr[0], v1 = xr[1];
#pragma unroll
      for (int j = 0; j < 8; ++j) {
        float xv = (float)v0[j];
        a0 = fmaf(xv, Wl[(s * 16 + j) * 3 + 0], a0);
        a1 = fmaf(xv, Wl[(s * 16 + j) * 3 + 1], a1);
        a2 = fmaf(xv, Wl[(s * 16 + j) * 3 + 2], a2);
      }
#pragma unroll
      for (int j = 0; j < 8; ++j) {
        float xv = (float)v1[j];
        a0 = fmaf(xv, Wl[(s * 16 + j + 8) * 3 + 0], a0);
        a1 = fmaf(xv, Wl[(s * 16 + j + 8) * 3 + 1], a1);
        a2 = fmaf(xv, Wl[(s * 16 + j + 8) * 3 + 2], a2);
      }
    }
    if (p < P0) {
      float* o = out + ((size_t)b * P0 + p) * 3;
      if (p == P0 - 1) { o[0] = 0.f; o[1] = 0.f; o[2] = 0.f; }
      else             { o[0] = a0;  o[1] = a1;  o[2] = a2; }
    }
  }
}

// ---------------------------------------------------------------------------
extern "C" void kernel_launch(void* const* d_in, const int* in_sizes, int n_in,
                              void* d_out, int out_size, void* d_ws, size_t ws_size,
                              hipStream_t stream) {
  (void)in_sizes; (void)n_in; (void)out_size;

  const float* x   = (const float*)d_in[0];
  const int*   S0  = (const int*)d_in[1];
  const float* D0  = (const float*)d_in[2];
  const float* U0  = (const float*)d_in[3];
  const int*   S1  = (const int*)d_in[4];
  const float* D1  = (const float*)d_in[5];
  const float* U1  = (const float*)d_in[6];
  const int*   S2  = (const int*)d_in[7];
  const float* D2  = (const float*)d_in[8];
  const float* U2  = (const float*)d_in[9];
  const int*   S3  = (const int*)d_in[10];
  const float* D3  = (const float*)d_in[11];
  const float* U3  = (const float*)d_in[12];
  const float* We0 = (const float*)d_in[13]; const float* be0 = (const float*)d_in[14];
  const float* We1 = (const float*)d_in[15]; const float* be1 = (const float*)d_in[16];
  const float* We2 = (const float*)d_in[17]; const float* be2 = (const float*)d_in[18];
  const float* We3 = (const float*)d_in[19]; const float* be3 = (const float*)d_in[20];
  const float* Wfe = (const float*)d_in[21]; const float* bfe = (const float*)d_in[22];
  const float* Wfd = (const float*)d_in[23]; const float* bfd = (const float*)d_in[24];
  const float* Wd0 = (const float*)d_in[25]; const float* bd0 = (const float*)d_in[26];
  const float* Wd1 = (const float*)d_in[27]; const float* bd1 = (const float*)d_in[28];
  const float* Wd2 = (const float*)d_in[29]; const float* bd2 = (const float*)d_in[30];
  const float* Wd3 = (const float*)d_in[31]; const float* bd3 = (const float*)d_in[32];
  const float* Wd4 = (const float*)d_in[33]; const float* bd4 = (const float*)d_in[34];

  char* ws = (char*)d_ws;
  u16*   zb   = (u16*)(ws + OFF_ZB);
  u16*   MbD0 = (u16*)(ws + OFF_MD0); u16* MbU0 = (u16*)(ws + OFF_MU0);
  u16*   MbD1 = (u16*)(ws + OFF_MD1); u16* MbU1 = (u16*)(ws + OFF_MU1);
  u16*   MbD2 = (u16*)(ws + OFF_MD2); u16* MbU2 = (u16*)(ws + OFF_MU2);
  u16*   MbD3 = (u16*)(ws + OFF_MD3); u16* MbU3 = (u16*)(ws + OFF_MU3);
  u16*   Wte1 = (u16*)(ws + OFF_WE1); u16* Wte2 = (u16*)(ws + OFF_WE2);
  u16*   Wte3 = (u16*)(ws + OFF_WE3); u16* Wtd0 = (u16*)(ws + OFF_WD0);
  u16*   Wtd1 = (u16*)(ws + OFF_WD1); u16* Wtd2 = (u16*)(ws + OFF_WD2);
  u16*   Wtd3 = (u16*)(ws + OFF_WD3); u16* Wt0  = (u16*)(ws + OFF_WT0);
  u16*   xt16 = (u16*)(ws + OFF_XT);
  float* fcp  = (float*)(ws + OFF_FCP);
  u16*   B0   = (u16*)(ws + OFF_B0);
  u16*   B1   = (u16*)(ws + OFF_B1);
  u16*   Pbuf = (u16*)(ws + OFF_PB);
  const bool sk = OFF_END <= ws_size;   // legacy split-K partials fit

  float* out_h = (float*)d_out;                       // [64][6891][3]
  float* out_z = out_h + (size_t)64 * P0 * 3;         // [64][128]

  auto cdiv = [](int a, int b) { return (a + b - 1) / b; };
  dim3 blk(256);

  // Split-K resample launcher (legacy 2-barrier kernel, fp16 partials).
  auto rs = [&](const u16* Mb, const u16* Bin, int Mtiles, int Ntiles, int Kpad, int N, int SK) {
    if (sk && SK > 1) {
      kgemm<false, 128, 0, false><<<dim3(Mtiles, Ntiles, SK), blk, 0, stream>>>(
          Mb, Bin, nullptr, nullptr, Pbuf, zb, Kpad, 0, 0, N);
      int mn = Mtiles * 128 * N;
      kred<<<cdiv(mn / 8, 256), blk, 0, stream>>>(Pbuf, B1, mn / 8, SK, (size_t)mn);
    } else {
      kgemm<false, 128, 0, false><<<dim3(Mtiles, Ntiles), blk, 0, stream>>>(
          Mb, Bin, nullptr, nullptr, B1, zb, Kpad, 0, 0, N);
    }
  };

  // ---- fused preprocessing (1 launch) ----
  PrepSrc ps{D0, U0, D1, U1, D2, U2, D3, U3, We1, We2, We3, Wd0, Wd1, Wd2, Wd3, We0, x};
  kprep<<<cdiv(CN_TOTAL, 256), blk, 0, stream>>>(ps, ws);

  // ---- encoder ----
  kgemm<true, 16, 3, true><<<dim3(432, 8), blk, 0, stream>>>(xt16, Wt0, S0, be0, B0, zb, 128, P0, P0p, 16);
  rs(MbD0, B0, 14, 8, 6912, 1024, 4);          // D0: validated legacy SK4 path
  kgemm<true, 32, 4, true><<<dim3(112, 8), blk, 0, stream>>>(B1, Wte1, S1, be1, B0, zb, 192, P1, 1792, 32);
  rs(MbD1, B0, 4, 16, 1792, 2048, 7);
  kgemm<true, 64, 5, true><<<dim3(32, 8), blk, 0, stream>>>(B1, Wte2, S2, be2, B0, zb, 320, P2, 512, 64);
  rs(MbD2, B0, 1, 32, 512, 4096, 4);
  kgemm<true, 64, 6, true><<<dim3(8, 8, 2), blk, 0, stream>>>(B1, Wte3, S3, be3, B0, zb, 576, P3, 128, 128);
  rs(MbD3, B0, 1, 64, 128, 8192, 1);

  // ---- bottleneck ----
  kfc_enc1<<<dim3(28, 2), blk, 0, stream>>>(B1, Wfe, fcp);
  kfc_dec<<<dim3(14, 8), blk, 0, stream>>>(fcp, bfe, out_z, Wfd, bfd, B0);

  // ---- decoder ----
  rs(MbU3, B0, 1, 64, 128, 8192, 1);
  kgemm<true, 32, 7, true><<<dim3(8, 8, 2), blk, 0, stream>>>(B1, Wtd0, S3, bd0, B0, zb, 1152, P3, 128, 64);
  rs(MbU2, B0, 4, 32, 128, 4096, 1);
  kgemm<true, 32, 6, true><<<dim3(32, 8), blk, 0, stream>>>(B1, Wtd1, S2, bd1, B0, zb, 576, P2, 512, 32);
  rs(MbU1, B0, 14, 16, 512, 2048, 2);
  kgemm<true, 32, 5, true><<<dim3(112, 8), blk, 0, stream>>>(B1, Wtd2, S1, bd2, B0, zb, 320, P1, 1792, 32);
  kgemm8<<<dim3(27, 8), dim3(512), 0, stream>>>(MbU0, B0, B1, 1792, 2048);   // U0: 2-buf counted pipeline
  kgemm<true, 16, 5, true, 1><<<dim3(432, 8), blk, 0, stream>>>(B1, Wtd3, S0, bd3, B0, zb, 320, P0, 0, 16);

  // ---- final ----
  kfinal<<<dim3(108, 8), blk, 0, stream>>>(B0, S0, Wd4, bd4, out_h);
}

// Round 14
// 390.987 us; speedup vs baseline: 1.7362x; 1.7362x over previous
//
#include <hip/hip_runtime.h>
#include <math.h>

typedef unsigned short u16;
typedef _Float16 f16;
typedef __attribute__((ext_vector_type(8))) _Float16 f16x8;
typedef __attribute__((ext_vector_type(4))) float f32x4;
typedef float4 __attribute__((aligned(4))) float4u;   // 4B-aligned vector load

constexpr int P0 = 6891, P1 = 1724, P2 = 432, P3 = 109, P4 = 28;
constexpr int P0p = 6912;

// ---- constexpr workspace layout (bytes, all 256-aligned) ----
constexpr size_t OFF_ZB   = 0;
constexpr size_t OFF_MD0  = OFF_ZB   + 256;
constexpr size_t OFF_MU0  = OFF_MD0  + (size_t)1792 * 6912 * 2;
constexpr size_t OFF_MD1  = OFF_MU0  + (size_t)6912 * 1792 * 2;
constexpr size_t OFF_MU1  = OFF_MD1  + (size_t)512 * 1792 * 2;
constexpr size_t OFF_MD2  = OFF_MU1  + (size_t)1792 * 512 * 2;
constexpr size_t OFF_MU2  = OFF_MD2  + (size_t)128 * 512 * 2;
constexpr size_t OFF_MD3  = OFF_MU2  + (size_t)512 * 128 * 2;
constexpr size_t OFF_MU3  = OFF_MD3  + (size_t)128 * 128 * 2;
constexpr size_t OFF_WE1  = OFF_MU3  + (size_t)128 * 128 * 2;
constexpr size_t OFF_WE2  = OFF_WE1  + (size_t)32 * 192 * 2;
constexpr size_t OFF_WE3  = OFF_WE2  + (size_t)64 * 320 * 2;
constexpr size_t OFF_WD0  = OFF_WE3  + (size_t)128 * 576 * 2;
constexpr size_t OFF_WD1  = OFF_WD0  + (size_t)64 * 1152 * 2;
constexpr size_t OFF_WD2  = OFF_WD1  + (size_t)32 * 576 * 2;
constexpr size_t OFF_WD3  = OFF_WD2  + (size_t)32 * 320 * 2;
constexpr size_t OFF_WT0  = OFF_WD3  + (size_t)16 * 320 * 2;
constexpr size_t OFF_XT   = OFF_WT0  + (size_t)16 * 128 * 2;
constexpr size_t OFF_FCP  = OFF_XT   + (size_t)6912 * 64 * 8 * 2;   // fp16 x-table [P0p][64][8]
constexpr size_t OFF_B0   = OFF_FCP  + (size_t)28 * 8192 * 4;
constexpr size_t OFF_B1   = OFF_B0   + (size_t)1024 * 6912 * 2;
constexpr size_t OFF_PB   = OFF_B1   + (size_t)6912 * 2048 * 2;
constexpr size_t OFF_END  = OFF_PB   + (size_t)14680064;            // legacy split-K partials

// ---- kprep segment sizes (items) ----
constexpr int CN_MD0 = 1792 * 864, CN_MU0 = 6912 * 224, CN_MD1 = 512 * 224,
              CN_MU1 = 1792 * 64, CN_MD2 = 128 * 64, CN_MU2 = 512 * 16,
              CN_MD3 = 128 * 16, CN_MU3 = 128 * 16,
              CN_W1 = 32 * 24, CN_W2 = 64 * 40, CN_W3 = 128 * 72,
              CN_V0 = 64 * 144, CN_V1 = 32 * 72, CN_V2 = 32 * 40, CN_V3 = 16 * 40,
              CN_W0 = 16 * 16, CN_XT = 6912 * 64, CN_ZB = 32;
constexpr int CN_TOTAL = CN_MD0 + CN_MU0 + CN_MD1 + CN_MU1 + CN_MD2 + CN_MU2 +
                         CN_MD3 + CN_MU3 + CN_W1 + CN_W2 + CN_W3 + CN_V0 + CN_V1 +
                         CN_V2 + CN_V3 + CN_W0 + CN_XT + CN_ZB;

__device__ __forceinline__ u16 f2h(float v) {
  f16 h = (f16)v;
  return __builtin_bit_cast(u16, h);
}
__device__ __forceinline__ float h2f(u16 u) {
  return (float)__builtin_bit_cast(f16, u);
}
__device__ __forceinline__ float eluf(float v) { return v > 0.f ? v : expm1f(v); }

__device__ __forceinline__ void gload16(const void* g, void* lds) {
  __builtin_amdgcn_global_load_lds(
      (const __attribute__((address_space(1))) unsigned int*)g,
      (__attribute__((address_space(3))) unsigned int*)lds, 16, 0, 0);
}

// ---------------------------------------------------------------------------
// Fused preprocessing.
// ---------------------------------------------------------------------------
struct PrepSrc {
  const float *D0, *U0, *D1, *U1, *D2, *U2, *D3, *U3;
  const float *We1, *We2, *We3, *Wd0, *Wd1, *Wd2, *Wd3;
  const float *We0, *x;
};

// M [P][Q] fp32 -> [Ppad][Qpad] fp16 zero-pad, 16B-chunk XOR-swizzled by p&7.
__device__ __forceinline__ void conv_m_item(const float* __restrict__ M, u16* __restrict__ out,
                                            int idx, int P, int Q, int Qpad) {
  int cpr = Qpad >> 3;
  int p = idx / cpr, cq = idx - p * cpr;
  int w0 = (cq << 3) & ~63;
  int q0 = w0 + (((cq & 7) ^ (p & 7)) << 3);
  uint4 pk;
  if (p < P && q0 + 8 <= Q) {
    const float* s = M + (size_t)p * Q + q0;
    float4 va = *(const float4u*)s;
    float4 vb = *(const float4u*)(s + 4);
    pk.x = f2h(va.x) | ((unsigned)f2h(va.y) << 16);
    pk.y = f2h(va.z) | ((unsigned)f2h(va.w) << 16);
    pk.z = f2h(vb.x) | ((unsigned)f2h(vb.y) << 16);
    pk.w = f2h(vb.z) | ((unsigned)f2h(vb.w) << 16);
  } else {
    u16 v[8];
#pragma unroll
    for (int j = 0; j < 8; ++j) {
      int q = q0 + j;
      float f = (p < P && q < Q) ? M[(size_t)p * Q + q] : 0.f;
      v[j] = f2h(f);
    }
    pk.x = v[0] | ((unsigned)v[1] << 16); pk.y = v[2] | ((unsigned)v[3] << 16);
    pk.z = v[4] | ((unsigned)v[5] << 16); pk.w = v[6] | ((unsigned)v[7] << 16);
  }
  *(uint4*)(out + ((size_t)idx << 3)) = pk;
}

// W [K][F] fp32 -> Wt [F][Kpad] fp16 transposed, zero-pad, swizzled by co&7.
__device__ __forceinline__ void conv_w_item(const float* __restrict__ W, u16* __restrict__ out,
                                            int idx, int K, int F, int Kpad) {
  int cpr = Kpad >> 3;
  int co = idx / cpr, ck = idx - co * cpr;
  int w0 = (ck << 3) & ~63;
  int k0 = w0 + (((ck & 7) ^ (co & 7)) << 3);
  u16 v[8];
#pragma unroll
  for (int j = 0; j < 8; ++j) {
    int k = k0 + j;
    float f = (k < K) ? W[(size_t)k * F + co] : 0.f;
    v[j] = f2h(f);
  }
  uint4 pk;
  pk.x = v[0] | ((unsigned)v[1] << 16); pk.y = v[2] | ((unsigned)v[3] << 16);
  pk.z = v[4] | ((unsigned)v[5] << 16); pk.w = v[6] | ((unsigned)v[7] << 16);
  *(uint4*)(out + ((size_t)idx << 3)) = pk;
}

// We0 [27 = s*3+c][16] -> Wt0 [16 co][128 k], k = s*8+c (FIN padded 3->8), swizzled.
__device__ __forceinline__ void conv_w0_item(const float* __restrict__ W, u16* __restrict__ out,
                                             int idx) {
  int co = idx >> 4, ck = idx & 15;
  int w0 = (ck << 3) & ~63;
  int k0 = w0 + (((ck & 7) ^ (co & 7)) << 3);
  u16 v[8];
#pragma unroll
  for (int j = 0; j < 8; ++j) {
    int k = k0 + j;
    int s = k >> 3, c = k & 7;
    float f = (s < 9 && c < 3) ? W[(size_t)(s * 3 + c) * 16 + co] : 0.f;
    v[j] = f2h(f);
  }
  uint4 pk;
  pk.x = v[0] | ((unsigned)v[1] << 16); pk.y = v[2] | ((unsigned)v[3] << 16);
  pk.z = v[4] | ((unsigned)v[5] << 16); pk.w = v[6] | ((unsigned)v[7] << 16);
  *(uint4*)(out + ((size_t)idx << 3)) = pk;
}

__global__ __launch_bounds__(256) void kprep(PrepSrc a, char* __restrict__ ws) {
  int i = blockIdx.x * 256 + threadIdx.x;
  if (i >= CN_TOTAL) return;
  if (i < CN_MD0) { conv_m_item(a.D0, (u16*)(ws + OFF_MD0), i, P1, P0, 6912); return; }
  i -= CN_MD0;
  if (i < CN_MU0) { conv_m_item(a.U0, (u16*)(ws + OFF_MU0), i, P0, P1, 1792); return; }
  i -= CN_MU0;
  if (i < CN_XT) {  // x [64][P0][3] fp32 -> xt16 [P0p][64][8] fp16 (f 3..7 = 0)
    u16* xt = (u16*)(ws + OFF_XT);
    int p = i >> 6, b = i & 63;
    float v0 = 0, v1 = 0, v2 = 0;
    if (p < P0) { const float* s = a.x + ((size_t)b * P0 + p) * 3; v0 = s[0]; v1 = s[1]; v2 = s[2]; }
    uint4 pk;
    pk.x = f2h(v0) | ((unsigned)f2h(v1) << 16);
    pk.y = f2h(v2);
    pk.z = 0; pk.w = 0;
    *(uint4*)(xt + ((size_t)i << 3)) = pk;
    return;
  }
  i -= CN_XT;
  if (i < CN_MD1) { conv_m_item(a.D1, (u16*)(ws + OFF_MD1), i, P2, P1, 1792); return; }
  i -= CN_MD1;
  if (i < CN_MU1) { conv_m_item(a.U1, (u16*)(ws + OFF_MU1), i, P1, P2, 512); return; }
  i -= CN_MU1;
  if (i < CN_MD2) { conv_m_item(a.D2, (u16*)(ws + OFF_MD2), i, P3, P2, 512); return; }
  i -= CN_MD2;
  if (i < CN_MU2) { conv_m_item(a.U2, (u16*)(ws + OFF_MU2), i, P2, P3, 128); return; }
  i -= CN_MU2;
  if (i < CN_MD3) { conv_m_item(a.D3, (u16*)(ws + OFF_MD3), i, P4, P3, 128); return; }
  i -= CN_MD3;
  if (i < CN_MU3) { conv_m_item(a.U3, (u16*)(ws + OFF_MU3), i, P3, P4, 128); return; }
  i -= CN_MU3;
  if (i < CN_W1) { conv_w_item(a.We1, (u16*)(ws + OFF_WE1), i, 144, 32, 192); return; }
  i -= CN_W1;
  if (i < CN_W2) { conv_w_item(a.We2, (u16*)(ws + OFF_WE2), i, 288, 64, 320); return; }
  i -= CN_W2;
  if (i < CN_W3) { conv_w_item(a.We3, (u16*)(ws + OFF_WE3), i, 576, 128, 576); return; }
  i -= CN_W3;
  if (i < CN_V0) { conv_w_item(a.Wd0, (u16*)(ws + OFF_WD0), i, 1152, 64, 1152); return; }
  i -= CN_V0;
  if (i < CN_V1) { conv_w_item(a.Wd1, (u16*)(ws + OFF_WD1), i, 576, 32, 576); return; }
  i -= CN_V1;
  if (i < CN_V2) { conv_w_item(a.Wd2, (u16*)(ws + OFF_WD2), i, 288, 32, 320); return; }
  i -= CN_V2;
  if (i < CN_V3) { conv_w_item(a.Wd3, (u16*)(ws + OFF_WD3), i, 288, 16, 320); return; }
  i -= CN_V3;
  if (i < CN_W0) { conv_w0_item(a.We0, (u16*)(ws + OFF_WT0), i); return; }
  i -= CN_W0;
  ((unsigned long long*)(ws + OFF_ZB))[i] = 0ull;  // zb
}

// ---------------------------------------------------------------------------
// kgemm8 (round-12 validated version): 256x256 tile, BK=32, 512 thr (8 waves
// 2x4), 3-deep counted-vmcnt pipeline with PHASED inner loop: 4 phases of
// {2 ds_read | 1 gload prefetch | 8-MFMA setprio cluster | sched_barrier}.
// 96 KB LDS, 1 block/CU (structural: acc[8][4]=128 VGPR forbids 2 blocks/CU —
// r13's launch_bounds(512,4) spilled acc to scratch, 795 MB writes, 6x slower).
// A and B FM-swizzled [rows][Kpad]. C plain [M][N] fp16. grid (M/256, N/256).
// ---------------------------------------------------------------------------
__global__ __launch_bounds__(512, 1) void kgemm8(const u16* __restrict__ A, const u16* __restrict__ B,
                                                 u16* __restrict__ C, int Kpad, int N) {
  __shared__ u16 lds[3 * 16384];   // 3 bufs x (A 8192 + B 8192) u16 = 96 KB
  const int t = threadIdx.x, l = t & 63;
  const int w = t >> 6, wr = w >> 2, wc = w & 3;
  const int pt = blockIdx.x * 256, nt = blockIdx.y * 256;
  const int NK = Kpad >> 5;

  f32x4 acc[8][4];
#pragma unroll
  for (int a = 0; a < 8; ++a)
#pragma unroll
    for (int b = 0; b < 4; ++b) acc[a][b] = (f32x4){0.f, 0.f, 0.f, 0.f};

  // ph 0/1: A halves; ph 2/3: B halves. Src read undoes producer swizzle.
  auto stage_chunk = [&](int qq, int ks, int ph) {
    int s = t + (ph & 1) * 512;
    int row = (s & 15) | ((s >> 6) << 4);
    int kc = (s >> 4) & 3;
    int slot = ((((ks & 1) << 2) + kc) ^ (row & 7));
    const u16* src;
    int base;
    if (ph < 2) {
      src = A + (size_t)(pt + row) * Kpad + ((ks >> 1) << 6) + (slot << 3);
      base = qq * 16384 + (s & ~63) * 8;
    } else {
      src = B + (size_t)(nt + row) * Kpad + ((ks >> 1) << 6) + (slot << 3);
      base = qq * 16384 + 8192 + (s & ~63) * 8;
    }
    gload16(src, &lds[base]);
  };

#pragma unroll
  for (int ph = 0; ph < 4; ++ph) stage_chunk(0, 0, ph);
  if (NK > 1)
#pragma unroll
    for (int ph = 0; ph < 4; ++ph) stage_chunk(1, 1, ph);

  for (int k = 0; k < NK; ++k) {
    asm volatile("s_waitcnt vmcnt(4)" ::: "memory");   // stage k landed; k+1 may fly
    __builtin_amdgcn_s_barrier();
    __builtin_amdgcn_sched_barrier(0);
    const int q = k % 3;
    const u16* bufA = &lds[q * 16384];
    const u16* bufB = bufA + 8192;
    const bool pre = (k + 2 < NK);
    const int ks2 = k + 2, q2 = (k + 2) % 3;

    f16x8 bv[4];
#pragma unroll
    for (int nf = 0; nf < 4; ++nf)
      bv[nf] = *(const f16x8*)&bufB[(wc * 4 + nf) * 512 + l * 8];

#pragma unroll
    for (int ph = 0; ph < 4; ++ph) {
      f16x8 a0 = *(const f16x8*)&bufA[(wr * 8 + 2 * ph) * 512 + l * 8];
      f16x8 a1 = *(const f16x8*)&bufA[(wr * 8 + 2 * ph + 1) * 512 + l * 8];
      if (pre) stage_chunk(q2, ks2, ph);
      __builtin_amdgcn_s_setprio(1);
#pragma unroll
      for (int nf = 0; nf < 4; ++nf) {
        acc[2 * ph][nf]     = __builtin_amdgcn_mfma_f32_16x16x32_f16(a0, bv[nf], acc[2 * ph][nf], 0, 0, 0);
        acc[2 * ph + 1][nf] = __builtin_amdgcn_mfma_f32_16x16x32_f16(a1, bv[nf], acc[2 * ph + 1][nf], 0, 0, 0);
      }
      __builtin_amdgcn_s_setprio(0);
      __builtin_amdgcn_sched_barrier(0);
    }
  }

#pragma unroll
  for (int mf = 0; mf < 8; ++mf) {
    int prow = pt + wr * 128 + mf * 16 + ((l >> 4) << 2);
#pragma unroll
    for (int nf = 0; nf < 4; ++nf) {
      int ncol = nt + wc * 64 + nf * 16 + (l & 15);
#pragma unroll
      for (int rg = 0; rg < 4; ++rg)
        C[(size_t)(prow + rg) * N + ncol] = f2h(acc[mf][nf][rg]);
    }
  }
}

// ---------------------------------------------------------------------------
// Unified MFMA GEMM — single-buffered 2-barrier loop (unchanged from r8).
// ---------------------------------------------------------------------------
template <bool GATHER, int TN, int LOG_FIN, bool DO_ELU, int OUT_MODE = 0>
__global__ __launch_bounds__(256) void kgemm(const u16* __restrict__ Asrc, const u16* __restrict__ Bsrc,
                                             const int* __restrict__ S, const float* __restrict__ bias,
                                             u16* __restrict__ Cout, const u16* __restrict__ zb,
                                             int Kpad, int Pn, int PpadC, int N) {
  constexpr int NF = TN / 16;
  __shared__ u16 Ash[128 * 64];
  __shared__ u16 Bsh[TN * 64];
  __shared__ int Sl[16 * 12];

  const int t = threadIdx.x, w = t >> 6, l = t & 63;
  int p0, b0 = 0, n0 = 0;
  if (GATHER) { p0 = blockIdx.x * 16; b0 = blockIdx.y * 8; n0 = blockIdx.z * TN; }
  else        { p0 = blockIdx.x * 128; n0 = blockIdx.y * 128; }

  if constexpr (GATHER) {
    for (int i = t; i < 144; i += 256) {
      int pp = p0 + i / 9;
      Sl[(i / 9) * 12 + (i % 9)] = (pp < Pn) ? S[pp * 9 + (i % 9)] : 0;
    }
    __syncthreads();
  }

  const int NK = Kpad >> 6;
  int NKs, ks0;
  if constexpr (GATHER) { NKs = NK; ks0 = 0; }
  else                  { NKs = NK / gridDim.z; ks0 = blockIdx.z * NKs; }
  f32x4 acc[2][NF];
#pragma unroll
  for (int a = 0; a < 2; ++a)
#pragma unroll
    for (int b = 0; b < NF; ++b) acc[a][b] = (f32x4){0.f, 0.f, 0.f, 0.f};

  auto stage = [&](int ks) {
#pragma unroll
    for (int g0 = 0; g0 < 4; ++g0) {
      int g = g0 * 4 + w;
      int r = g * 8 + (l >> 3);
      const u16* src;
      if constexpr (GATHER) {
        int c = (l & 7) ^ (r & 7);
        int k = ks * 64 + c * 8;
        int s = k >> LOG_FIN;
        if (s < 9) {
          int kk = k & ((1 << LOG_FIN) - 1);
          int sv = Sl[(r & 15) * 12 + s];
          src = Asrc + (((size_t)(sv << 6) + b0 + (r >> 4)) << LOG_FIN) + kk;
        } else src = zb;
      } else {
        src = Asrc + (size_t)(p0 + r) * Kpad + ks * 64 + (l & 7) * 8;
      }
      gload16(src, &Ash[g * 512]);
    }
#pragma unroll
    for (int g0 = 0; g0 < (TN / 8 + 3) / 4; ++g0) {
      int g = g0 * 4 + w;
      if (g < TN / 8) {
        int r = g * 8 + (l >> 3);
        const u16* src = Bsrc + (size_t)(n0 + r) * Kpad + ks * 64 + (l & 7) * 8;
        gload16(src, &Bsh[g * 512]);
      }
    }
  };

  auto compute = [&]() {
#pragma unroll
    for (int kh = 0; kh < 2; ++kh) {
      f16x8 av[2], bv[NF];
#pragma unroll
      for (int mf = 0; mf < 2; ++mf) {
        int r = w * 32 + mf * 16 + (l & 15);
        int c = kh * 4 + (l >> 4);
        av[mf] = *(const f16x8*)&Ash[r * 64 + ((c ^ (r & 7)) << 3)];
      }
#pragma unroll
      for (int nf = 0; nf < NF; ++nf) {
        int r = nf * 16 + (l & 15);
        int c = kh * 4 + (l >> 4);
        bv[nf] = *(const f16x8*)&Bsh[r * 64 + ((c ^ (r & 7)) << 3)];
      }
#pragma unroll
      for (int mf = 0; mf < 2; ++mf)
#pragma unroll
        for (int nf = 0; nf < NF; ++nf)
          acc[mf][nf] = __builtin_amdgcn_mfma_f32_16x16x32_f16(av[mf], bv[nf], acc[mf][nf], 0, 0, 0);
    }
  };

  for (int i = 0; i < NKs; ++i) {
    stage(ks0 + i);
    __syncthreads();
    compute();
    __syncthreads();
  }

  if constexpr (GATHER && OUT_MODE == 1) {
    u16* T = &Ash[0];   // viewed as [16][136]
    int co = l & 15;
    float bb = bias[co];
    int prow = (l >> 4) << 2;
#pragma unroll
    for (int mf = 0; mf < 2; ++mf) {
      int ncol = (w * 2 + mf) * 16 + co;
#pragma unroll
      for (int rg = 0; rg < 4; ++rg) {
        float v = acc[mf][0][rg] + bb;
        if (DO_ELU) v = eluf(v);
        if (p0 + prow + rg >= Pn - 1) v = 0.f;
        T[(prow + rg) * 136 + ncol] = f2h(v);
      }
    }
    __syncthreads();
    int r = t >> 4, c8 = (t & 15) << 3;
    uint4 pk = *(const uint4*)&T[r * 136 + c8];
    *(uint4*)(Cout + (size_t)(p0 + r) * (64 * TN) + (size_t)blockIdx.y * 128 + c8) = pk;
  } else if constexpr (GATHER) {
#pragma unroll
    for (int nf = 0; nf < NF; ++nf) {
      int co = n0 + nf * 16 + (l & 15);
      float bb = bias[co];
#pragma unroll
      for (int mf = 0; mf < 2; ++mf) {
        int b = b0 + w * 2 + mf;
        int n = b * N + co;
        int pbase = p0 + ((l >> 4) << 2);
        u16 hv[4];
#pragma unroll
        for (int rg = 0; rg < 4; ++rg) {
          float v = acc[mf][nf][rg] + bb;
          if (DO_ELU) v = eluf(v);
          if (pbase + rg >= Pn - 1) v = 0.f;
          hv[rg] = f2h(v);
        }
        int slot = ((pbase >> 3) & 7) ^ (n & 7);
        u16* dst = Cout + (size_t)n * PpadC + (pbase & ~63) + (slot << 3) + (pbase & 7);
        uint2 pk;
        pk.x = hv[0] | ((unsigned)hv[1] << 16);
        pk.y = hv[2] | ((unsigned)hv[3] << 16);
        *(uint2*)dst = pk;
      }
    }
  } else {
    u16* Cb = Cout + (size_t)blockIdx.z * ((size_t)gridDim.x * 128 * N);
#pragma unroll
    for (int mf = 0; mf < 2; ++mf) {
      int pb = p0 + w * 32 + mf * 16 + ((l >> 4) << 2);
#pragma unroll
      for (int nf = 0; nf < NF; ++nf) {
        int n = n0 + nf * 16 + (l & 15);
#pragma unroll
        for (int rg = 0; rg < 4; ++rg)
          Cb[(size_t)(pb + rg) * N + n] = f2h(acc[mf][nf][rg]);
      }
    }
  }
}

// Reduce split-K fp16 partial slices: out[i] = sum_z part[z*slice + i].
__global__ __launch_bounds__(256) void kred(const u16* __restrict__ part, u16* __restrict__ out,
                                            int mn8, int sk, size_t slice) {
  int i = blockIdx.x * 256 + threadIdx.x;
  if (i >= mn8) return;
  size_t base = (size_t)i * 8;
  float s[8] = {};
  for (int z = 0; z < sk; ++z) {
    uint4 u = *(const uint4*)(part + z * slice + base);
    s[0] += h2f((u16)u.x); s[1] += h2f((u16)(u.x >> 16));
    s[2] += h2f((u16)u.y); s[3] += h2f((u16)(u.y >> 16));
    s[4] += h2f((u16)u.z); s[5] += h2f((u16)(u.z >> 16));
    s[6] += h2f((u16)u.w); s[7] += h2f((u16)(u.w >> 16));
  }
  uint4 o;
  o.x = f2h(s[0]) | ((unsigned)f2h(s[1]) << 16);
  o.y = f2h(s[2]) | ((unsigned)f2h(s[3]) << 16);
  o.z = f2h(s[4]) | ((unsigned)f2h(s[5]) << 16);
  o.w = f2h(s[6]) | ((unsigned)f2h(s[7]) << 16);
  *(uint4*)(out + base) = o;
}

// ---------------------------------------------------------------------------
// FC encode split-K stage 1. grid (28, 2), 256 thr.
// ---------------------------------------------------------------------------
__global__ __launch_bounds__(256) void kfc_enc1(const u16* __restrict__ h, const float* __restrict__ W,
                                                float* __restrict__ partial) {
  __shared__ float hs[64][128];
  __shared__ float wsh[128][64];
  int p = blockIdx.x, nh = blockIdx.y, t = threadIdx.x;
  for (int i = t; i < 8192; i += 256) hs[i >> 7][i & 127] = h2f(h[(size_t)p * 8192 + i]);
  for (int i = t; i < 128 * 64; i += 256) {
    int kk = i >> 6, jj = i & 63;
    wsh[kk][jj] = W[(size_t)(p * 128 + kk) * 128 + nh * 64 + jj];
  }
  __syncthreads();
  int j = t & 63, bg = t >> 6;
  float acc[16] = {};
  for (int k = 0; k < 128; ++k) {
    float wv = wsh[k][j];
#pragma unroll
    for (int i = 0; i < 16; ++i) acc[i] = fmaf(hs[bg * 16 + i][k], wv, acc[i]);
  }
#pragma unroll
  for (int i = 0; i < 16; ++i)
    partial[((size_t)p * 64 + bg * 16 + i) * 128 + nh * 64 + j] = acc[i];
}

// FC decode (fused z-reduction). grid (14, 8).
__global__ __launch_bounds__(256) void kfc_dec(const float* __restrict__ partial,
                                               const float* __restrict__ bfe, float* __restrict__ z,
                                               const float* __restrict__ W,
                                               const float* __restrict__ bias, u16* __restrict__ out) {
  __shared__ float zs[8][128];
  int t = threadIdx.x, b0 = blockIdx.y * 8;
  for (int i = t; i < 8 * 128; i += 256) {
    int bb = i >> 7, j = i & 127;
    float s = bfe[j];
    for (int p = 0; p < 28; ++p) s += partial[(size_t)p * 8192 + (b0 + bb) * 128 + j];
    zs[bb][j] = s;
    if (blockIdx.x == 0) z[(b0 + bb) * 128 + j] = s;
  }
  __syncthreads();
  int m = blockIdx.x * 256 + t;
  float bb = bias[m];
  float acc[8];
#pragma unroll
  for (int i = 0; i < 8; ++i) acc[i] = bb;
  for (int k = 0; k < 128; ++k) {
    float wv = W[(size_t)k * 3584 + m];
#pragma unroll
    for (int i = 0; i < 8; ++i) acc[i] = fmaf(zs[i][k], wv, acc[i]);
  }
  int p = m >> 7, f = m & 127;
  int slot0 = p >> 3;
#pragma unroll
  for (int i = 0; i < 8; ++i) {
    int n = (b0 + i) * 128 + f;
    int slot = slot0 ^ (n & 7);
    out[(size_t)n * 128 + (slot << 3) + (p & 7)] = f2h(acc[i]);
  }
}

// ---------------------------------------------------------------------------
// final conv 16->3 identity; VM fp16 in [6912][1024], fp32 out [64][P0][3].
// ---------------------------------------------------------------------------
__global__ __launch_bounds__(256) void kfinal(const u16* __restrict__ x, const int* __restrict__ S,
                                              const float* __restrict__ W, const float* __restrict__ bias,
                                              float* __restrict__ out) {
  __shared__ float Wl[432];
  __shared__ int Sl[64 * 9];
  int t = threadIdx.x;
  for (int i = t; i < 432; i += 256) Wl[i] = W[i];
  int pblk = blockIdx.x * 64;
  for (int i = t; i < 64 * 9; i += 256) {
    int pp = pblk + i / 9;
    Sl[i] = (pp < P0) ? S[pp * 9 + (i % 9)] : 0;
  }
  __syncthreads();
  int lane = t & 63, w = t >> 6;
  int p = pblk + lane;
  float b0v = bias[0], b1v = bias[1], b2v = bias[2];
  int idxs[9];
#pragma unroll
  for (int s = 0; s < 9; ++s) idxs[s] = Sl[lane * 9 + s];
#pragma unroll
  for (int bi = 0; bi < 2; ++bi) {
    int b = blockIdx.y * 8 + w * 2 + bi;
    float a0 = b0v, a1 = b1v, a2 = b2v;
    for (int s = 0; s < 9; ++s) {
      const f16x8* xr = (const f16x8*)(x + ((size_t)idxs[s] * 64 + b) * 16);
      f16x8 v0 = xr[0], v1 = xr[1];
#pragma unroll
      for (int j = 0; j < 8; ++j) {
        float xv = (float)v0[j];
        a0 = fmaf(xv, Wl[(s * 16 + j) * 3 + 0], a0);
        a1 = fmaf(xv, Wl[(s * 16 + j) * 3 + 1], a1);
        a2 = fmaf(xv, Wl[(s * 16 + j) * 3 + 2], a2);
      }
#pragma unroll
      for (int j = 0; j < 8; ++j) {
        float xv = (float)v1[j];
        a0 = fmaf(xv, Wl[(s * 16 + j + 8) * 3 + 0], a0);
        a1 = fmaf(xv, Wl[(s * 16 + j + 8) * 3 + 1], a1);
        a2 = fmaf(xv, Wl[(s * 16 + j + 8) * 3 + 2], a2);
      }
    }
    if (p < P0) {
      float* o = out + ((size_t)b * P0 + p) * 3;
      if (p == P0 - 1) { o[0] = 0.f; o[1] = 0.f; o[2] = 0.f; }
      else             { o[0] = a0;  o[1] = a1;  o[2] = a2; }
    }
  }
}

// ---------------------------------------------------------------------------
extern "C" void kernel_launch(void* const* d_in, const int* in_sizes, int n_in,
                              void* d_out, int out_size, void* d_ws, size_t ws_size,
                              hipStream_t stream) {
  (void)in_sizes; (void)n_in; (void)out_size;

  const float* x   = (const float*)d_in[0];
  const int*   S0  = (const int*)d_in[1];
  const float* D0  = (const float*)d_in[2];
  const float* U0  = (const float*)d_in[3];
  const int*   S1  = (const int*)d_in[4];
  const float* D1  = (const float*)d_in[5];
  const float* U1  = (const float*)d_in[6];
  const int*   S2  = (const int*)d_in[7];
  const float* D2  = (const float*)d_in[8];
  const float* U2  = (const float*)d_in[9];
  const int*   S3  = (const int*)d_in[10];
  const float* D3  = (const float*)d_in[11];
  const float* U3  = (const float*)d_in[12];
  const float* We0 = (const float*)d_in[13]; const float* be0 = (const float*)d_in[14];
  const float* We1 = (const float*)d_in[15]; const float* be1 = (const float*)d_in[16];
  const float* We2 = (const float*)d_in[17]; const float* be2 = (const float*)d_in[18];
  const float* We3 = (const float*)d_in[19]; const float* be3 = (const float*)d_in[20];
  const float* Wfe = (const float*)d_in[21]; const float* bfe = (const float*)d_in[22];
  const float* Wfd = (const float*)d_in[23]; const float* bfd = (const float*)d_in[24];
  const float* Wd0 = (const float*)d_in[25]; const float* bd0 = (const float*)d_in[26];
  const float* Wd1 = (const float*)d_in[27]; const float* bd1 = (const float*)d_in[28];
  const float* Wd2 = (const float*)d_in[29]; const float* bd2 = (const float*)d_in[30];
  const float* Wd3 = (const float*)d_in[31]; const float* bd3 = (const float*)d_in[32];
  const float* Wd4 = (const float*)d_in[33]; const float* bd4 = (const float*)d_in[34];

  char* ws = (char*)d_ws;
  u16*   zb   = (u16*)(ws + OFF_ZB);
  u16*   MbD0 = (u16*)(ws + OFF_MD0); u16* MbU0 = (u16*)(ws + OFF_MU0);
  u16*   MbD1 = (u16*)(ws + OFF_MD1); u16* MbU1 = (u16*)(ws + OFF_MU1);
  u16*   MbD2 = (u16*)(ws + OFF_MD2); u16* MbU2 = (u16*)(ws + OFF_MU2);
  u16*   MbD3 = (u16*)(ws + OFF_MD3); u16* MbU3 = (u16*)(ws + OFF_MU3);
  u16*   Wte1 = (u16*)(ws + OFF_WE1); u16* Wte2 = (u16*)(ws + OFF_WE2);
  u16*   Wte3 = (u16*)(ws + OFF_WE3); u16* Wtd0 = (u16*)(ws + OFF_WD0);
  u16*   Wtd1 = (u16*)(ws + OFF_WD1); u16* Wtd2 = (u16*)(ws + OFF_WD2);
  u16*   Wtd3 = (u16*)(ws + OFF_WD3); u16* Wt0  = (u16*)(ws + OFF_WT0);
  u16*   xt16 = (u16*)(ws + OFF_XT);
  float* fcp  = (float*)(ws + OFF_FCP);
  u16*   B0   = (u16*)(ws + OFF_B0);
  u16*   B1   = (u16*)(ws + OFF_B1);
  u16*   Pbuf = (u16*)(ws + OFF_PB);
  const bool sk = OFF_END <= ws_size;   // legacy split-K partials fit

  float* out_h = (float*)d_out;                       // [64][6891][3]
  float* out_z = out_h + (size_t)64 * P0 * 3;         // [64][128]

  auto cdiv = [](int a, int b) { return (a + b - 1) / b; };
  dim3 blk(256);

  // Split-K resample launcher (legacy 2-barrier kernel, fp16 partials).
  auto rs = [&](const u16* Mb, const u16* Bin, int Mtiles, int Ntiles, int Kpad, int N, int SK) {
    if (sk && SK > 1) {
      kgemm<false, 128, 0, false><<<dim3(Mtiles, Ntiles, SK), blk, 0, stream>>>(
          Mb, Bin, nullptr, nullptr, Pbuf, zb, Kpad, 0, 0, N);
      int mn = Mtiles * 128 * N;
      kred<<<cdiv(mn / 8, 256), blk, 0, stream>>>(Pbuf, B1, mn / 8, SK, (size_t)mn);
    } else {
      kgemm<false, 128, 0, false><<<dim3(Mtiles, Ntiles), blk, 0, stream>>>(
          Mb, Bin, nullptr, nullptr, B1, zb, Kpad, 0, 0, N);
    }
  };

  // ---- fused preprocessing (1 launch) ----
  PrepSrc ps{D0, U0, D1, U1, D2, U2, D3, U3, We1, We2, We3, Wd0, Wd1, Wd2, Wd3, We0, x};
  kprep<<<cdiv(CN_TOTAL, 256), blk, 0, stream>>>(ps, ws);

  // ---- encoder ----
  kgemm<true, 16, 3, true><<<dim3(432, 8), blk, 0, stream>>>(xt16, Wt0, S0, be0, B0, zb, 128, P0, P0p, 16);
  rs(MbD0, B0, 14, 8, 6912, 1024, 4);          // D0: validated legacy SK4 path
  kgemm<true, 32, 4, true><<<dim3(112, 8), blk, 0, stream>>>(B1, Wte1, S1, be1, B0, zb, 192, P1, 1792, 32);
  rs(MbD1, B0, 4, 16, 1792, 2048, 7);
  kgemm<true, 64, 5, true><<<dim3(32, 8), blk, 0, stream>>>(B1, Wte2, S2, be2, B0, zb, 320, P2, 512, 64);
  rs(MbD2, B0, 1, 32, 512, 4096, 4);
  kgemm<true, 64, 6, true><<<dim3(8, 8, 2), blk, 0, stream>>>(B1, Wte3, S3, be3, B0, zb, 576, P3, 128, 128);
  rs(MbD3, B0, 1, 64, 128, 8192, 1);

  // ---- bottleneck ----
  kfc_enc1<<<dim3(28, 2), blk, 0, stream>>>(B1, Wfe, fcp);
  kfc_dec<<<dim3(14, 8), blk, 0, stream>>>(fcp, bfe, out_z, Wfd, bfd, B0);

  // ---- decoder ----
  rs(MbU3, B0, 1, 64, 128, 8192, 1);
  kgemm<true, 32, 7, true><<<dim3(8, 8, 2), blk, 0, stream>>>(B1, Wtd0, S3, bd0, B0, zb, 1152, P3, 128, 64);
  rs(MbU2, B0, 4, 32, 128, 4096, 1);
  kgemm<true, 32, 6, true><<<dim3(32, 8), blk, 0, stream>>>(B1, Wtd1, S2, bd1, B0, zb, 576, P2, 512, 32);
  rs(MbU1, B0, 14, 16, 512, 2048, 2);
  kgemm<true, 32, 5, true><<<dim3(112, 8), blk, 0, stream>>>(B1, Wtd2, S1, bd2, B0, zb, 320, P1, 1792, 32);
  kgemm8<<<dim3(27, 8), dim3(512), 0, stream>>>(MbU0, B0, B1, 1792, 2048);   // U0: phased pipeline (r12)
  kgemm<true, 16, 5, true, 1><<<dim3(432, 8), blk, 0, stream>>>(B1, Wtd3, S0, bd3, B0, zb, 320, P0, 0, 16);

  // ---- final ----
  kfinal<<<dim3(108, 8), blk, 0, stream>>>(B0, S0, Wd4, bd4, out_h);
}